// Round 6
// baseline (2614.034 us; speedup 1.0000x reference)
//
#include <hip/hip_runtime.h>

// RecursiveLSTM: B=1024, T=96, H=50, num_pred=12.
// Round-5 lesson (measured): EVERY LDS instruction costs ~12 cyc of the
// per-CU DS pipe, broadcast or not -> 70 ds_read/wave/step = 3360 cyc/step.
// Fix: h is broadcast through the VALU, not LDS. After a redundant per-wave
// update, lane j holds h[j] (one reg per batch); the 50-dot uses
// v_readlane (h -> SGPR) + v_fma with the SGPR operand. LDS per wave-step
// drops to 13 weight b128 + 5 gate-exchange b128 + 1 xv read (~230 cyc).
// NB=4 batches/block amortizes the weight stream 4x. Grid=256 -> 1 block/CU.
// Wave w = gate-type w (lanes 0..49 = unit j); all waves redundantly update
// all 4 batches' (h,c) so readlane stays intra-wave.

#define HSZ   50
#define G4    200
#define TLEN  96
#define MAXP  16
#define NB    4

__device__ __forceinline__ float tanh_(float x) {
    return 1.0f - 2.0f / (__expf(2.0f * x) + 1.0f);   // NaN-safe at large |x|
}
// a = m*sigmoid(m*acc) + (1-m): m=1 -> sigmoid, m=2 -> tanh
__device__ __forceinline__ float gatefn_(float a, float m, float add) {
    return fmaf(m, 1.0f / (1.0f + __expf(-m * a)), add);
}
__device__ __forceinline__ float rl_(float v, int k) {   // lane-k broadcast via SGPR
    return __int_as_float(__builtin_amdgcn_readlane(__float_as_int(v), k));
}

__global__ __launch_bounds__(256)
void rec_lstm_kernel(const float* __restrict__ x,
                     const float* __restrict__ W_ih,
                     const float* __restrict__ W_hh,
                     const float* __restrict__ b_ih,
                     const float* __restrict__ b_hh,
                     const float* __restrict__ W_fc,
                     const float* __restrict__ b_fc,
                     const int*   __restrict__ num_pred,
                     float*       __restrict__ out)
{
    const int  tid  = threadIdx.x;
    const int  wave = tid >> 6;
    const int  lane = tid & 63;
    const bool act  = (lane < HSZ);
    const int  j    = act ? lane : HSZ - 1;     // unit owned (clamped, benign dup)
    const int  g    = wave * HSZ + j;           // gate row owned
    const int  b0   = blockIdx.x * NB;

    __shared__ __align__(16) float W4[13][G4][4];       // W4[k4][g][kk] = W_hh[g][4k4+kk]
    __shared__ __align__(16) float gbuf[2][4][HSZ][4];  // [par][type][unit][batch]
    __shared__ __align__(16) float xp4[(TLEN + MAXP) * 4]; // x ++ preds, batch-interleaved

    // ---- one-time staging ----
    for (int i = tid; i < 13 * G4 * 4; i += 256) {
        const int k4 = i / (G4 * 4), r = i % (G4 * 4), gg = r >> 2, kk = r & 3;
        const int k  = 4 * k4 + kk;
        W4[k4][gg][kk] = (k < HSZ) ? W_hh[gg * HSZ + k] : 0.f;   // zero-pad k=50..51
    }
    for (int i = tid; i < NB * TLEN; i += 256) {
        const int bb = i / TLEN, t = i % TLEN;
        xp4[t * 4 + bb] = x[(b0 + bb) * TLEN + t];
    }
    const float wih  = W_ih[g];
    const float bsum = b_ih[g] + b_hh[g];
    const float wfc  = act ? W_fc[lane] : 0.f;
    const float bfc  = b_fc[0];
    const int   NP   = num_pred[0];
    const float m_   = (wave == 2) ? 2.f : 1.f;   // wave 2 owns g-gates -> tanh
    const float add_ = 1.f - m_;

    __syncthreads();

    int par = 0;
    for (int p = 0; p < NP; ++p) {
        // (h,c) for unit j, all 4 batches, in registers; redundant per wave
        float h0 = 0.f, h1 = 0.f, h2 = 0.f, h3 = 0.f;
        float c0 = 0.f, c1 = 0.f, c2 = 0.f, c3 = 0.f;

        for (int t = 0; t < TLEN; ++t) {
            const float4 xv = *(const float4*)&xp4[(p + t) * 4];  // 1 LDS read
            float a0 = fmaf(wih, xv.x, bsum);
            float a1 = fmaf(wih, xv.y, bsum);
            float a2 = fmaf(wih, xv.z, bsum);
            float a3 = fmaf(wih, xv.w, bsum);
            #pragma unroll
            for (int k4 = 0; k4 < 13; ++k4) {
                const float4 wv = *(const float4*)&W4[k4][g][0];  // 13 LDS reads
                #pragma unroll
                for (int kk = 0; kk < 4; ++kk) {
                    const int   k  = 4 * k4 + kk;                 // 50,51 -> w=0
                    const float wk = (kk == 0) ? wv.x : (kk == 1) ? wv.y
                                   : (kk == 2) ? wv.z : wv.w;
                    a0 = fmaf(wk, rl_(h0, k), a0);   // readlane: h via SGPR, no LDS
                    a1 = fmaf(wk, rl_(h1, k), a1);
                    a2 = fmaf(wk, rl_(h2, k), a2);
                    a3 = fmaf(wk, rl_(h3, k), a3);
                }
            }
            if (act) {   // own gate, 4 batches -> one b128 write
                float4 gv;
                gv.x = gatefn_(a0, m_, add_);
                gv.y = gatefn_(a1, m_, add_);
                gv.z = gatefn_(a2, m_, add_);
                gv.w = gatefn_(a3, m_, add_);
                *(float4*)&gbuf[par][wave][lane][0] = gv;
            }
            __syncthreads();                          // the ONE barrier per step

            {   // redundant update of unit j, all 4 batches (4 b128 reads)
                const float4 gi = *(const float4*)&gbuf[par][0][j][0];
                const float4 gf = *(const float4*)&gbuf[par][1][j][0];
                const float4 gg = *(const float4*)&gbuf[par][2][j][0];
                const float4 go = *(const float4*)&gbuf[par][3][j][0];
                c0 = fmaf(gf.x, c0, gi.x * gg.x);  h0 = go.x * tanh_(c0);
                c1 = fmaf(gf.y, c1, gi.y * gg.y);  h1 = go.y * tanh_(c1);
                c2 = fmaf(gf.z, c2, gi.z * gg.z);  h2 = go.z * tanh_(c2);
                c3 = fmaf(gf.w, c3, gi.w * gg.w);  h3 = go.w * tanh_(c3);
            }
            par ^= 1;
        }

        // ---- FC head: wave w reduces batch w ----
        const float hsel = (wave == 0) ? h0 : (wave == 1) ? h1 : (wave == 2) ? h2 : h3;
        float v = act ? hsel * wfc : 0.f;
        #pragma unroll
        for (int off = 32; off >= 1; off >>= 1) v += __shfl_down(v, off, 64);
        if (lane == 0) {
            const float pr = v + bfc;
            xp4[(TLEN + p) * 4 + wave] = pr;          // feedback; first read is
            out[(b0 + wave) * NP + p] = pr;           // >=95 barriers later
        }
    }
}

extern "C" void kernel_launch(void* const* d_in, const int* in_sizes, int n_in,
                              void* d_out, int out_size, void* d_ws, size_t ws_size,
                              hipStream_t stream)
{
    const float* x    = (const float*)d_in[0];
    const float* W_ih = (const float*)d_in[1];
    const float* W_hh = (const float*)d_in[2];
    const float* b_ih = (const float*)d_in[3];
    const float* b_hh = (const float*)d_in[4];
    const float* W_fc = (const float*)d_in[5];
    const float* b_fc = (const float*)d_in[6];
    const int*   np   = (const int*)d_in[7];
    float* out = (float*)d_out;

    const int B = in_sizes[0] / TLEN;   // 1024
    rec_lstm_kernel<<<B / NB, 256, 0, stream>>>(x, W_ih, W_hh, b_ih, b_hh,
                                                W_fc, b_fc, np, out);
}